// Round 7
// baseline (644.581 us; speedup 1.0000x reference)
//
#include <hip/hip_runtime.h>
#include <hip/hip_bf16.h>

typedef unsigned short u16;
typedef unsigned int   u32;
typedef __attribute__((ext_vector_type(8))) short short8;   // 8 x bf16 bits (4 VGPR)
typedef __attribute__((ext_vector_type(4))) short short4v;  // 4 x bf16 bits (8 B)
typedef __attribute__((ext_vector_type(4))) float f32x4;    // MFMA 16x16 accumulator

// round-to-nearest-even f32 -> bf16 (finite inputs only)
__device__ __forceinline__ u16 f2bf(float f) {
  u32 u = __float_as_uint(f);
  u32 r = (u + 0x7fffu + ((u >> 16) & 1u)) >> 16;
  return (u16)r;
}
__device__ __forceinline__ short8 cvt8(const float4 a, const float4 b) {
  short8 o;
  o[0]=(short)f2bf(a.x); o[1]=(short)f2bf(a.y); o[2]=(short)f2bf(a.z); o[3]=(short)f2bf(a.w);
  o[4]=(short)f2bf(b.x); o[5]=(short)f2bf(b.y); o[6]=(short)f2bf(b.z); o[7]=(short)f2bf(b.w);
  return o;
}

// ---------------------------------------------------------------------------
// Weight pre-convert: qkv_w [768][256] fp32 -> bf16, proj_w [256][256] -> bf16
// ---------------------------------------------------------------------------
__global__ __launch_bounds__(256) void wcvt_kernel(
    const float* __restrict__ qkvw, const float* __restrict__ pw,
    u16* __restrict__ wq, u16* __restrict__ wp) {
  const int e = (blockIdx.x * 256 + threadIdx.x) * 4;  // 256 blocks -> 262144
  if (e < 196608) {
    const float4 v = *(const float4*)(qkvw + e);
    short4v o; o[0]=(short)f2bf(v.x); o[1]=(short)f2bf(v.y);
    o[2]=(short)f2bf(v.z); o[3]=(short)f2bf(v.w);
    *(short4v*)(wq + e) = o;
  } else {
    const int e2 = e - 196608;
    const float4 v = *(const float4*)(pw + e2);
    short4v o; o[0]=(short)f2bf(v.x); o[1]=(short)f2bf(v.y);
    o[2]=(short)f2bf(v.z); o[3]=(short)f2bf(v.w);
    *(short4v*)(wp + e2) = o;
  }
}

// ---------------------------------------------------------------------------
// CPB MLP: table[225][8] = relu(coords @ w1^T + b1) @ w2^T   (fp32 math)
// ---------------------------------------------------------------------------
__global__ __launch_bounds__(256) void cpb_kernel(
    const float* __restrict__ ct, const float* __restrict__ w1,
    const float* __restrict__ b1, const float* __restrict__ w2,
    float* __restrict__ table) {
  const int r = blockIdx.x;            // 0..224
  const int t = threadIdx.x;           // 0..255
  const int lane = t & 63, wave = t >> 6;
  const float c0 = ct[r * 2 + 0];
  const float c1 = ct[r * 2 + 1];
  float acc[8] = {0.f, 0.f, 0.f, 0.f, 0.f, 0.f, 0.f, 0.f};
  for (int j = t; j < 512; j += 256) {
    float hid = fmaxf(c0 * w1[j * 2] + c1 * w1[j * 2 + 1] + b1[j], 0.f);
#pragma unroll
    for (int hh = 0; hh < 8; ++hh) acc[hh] += hid * w2[hh * 512 + j];
  }
#pragma unroll
  for (int hh = 0; hh < 8; ++hh)
#pragma unroll
    for (int off = 1; off < 64; off <<= 1) acc[hh] += __shfl_xor(acc[hh], off);
  __shared__ float red[4][8];
  if (lane == 0)
#pragma unroll
    for (int hh = 0; hh < 8; ++hh) red[wave][hh] = acc[hh];
  __syncthreads();
  if (t < 8) table[r * 8 + t] = red[0][t] + red[1][t] + red[2][t] + red[3][t];
}

// ---------------------------------------------------------------------------
// bmP[w][h][m][l][j] = 16*sigmoid(table[rel[m*64 + j*16+l]][h]) + mask[w][m][j*16+l]
// Permuted so a softmax lane (l15) reads its 4 values as ONE float4.
// fp32, 64*8*64*64 = 8 MB.
// ---------------------------------------------------------------------------
__global__ __launch_bounds__(256) void bm_kernel(
    const float* __restrict__ table, const int* __restrict__ rel,
    const float* __restrict__ mask, float* __restrict__ bmP) {
  const int g = blockIdx.x * 256 + threadIdx.x;   // 0..524287
  const int w = g >> 13;
  const int h = (g >> 10) & 7;
  const int m = (g >> 4) & 63;
  const int l = g & 15;
  float4 o;
#pragma unroll
  for (int j = 0; j < 4; ++j) {
    const int c = j * 16 + l;
    const float t = table[rel[m * 64 + c] * 8 + h];
    o[j] = 16.f / (1.f + __expf(-t)) + mask[(size_t)w * 4096 + m * 64 + c];
  }
  *(float4*)(bmP + ((((size_t)w * 8 + h) * 64 + m) * 64 + l * 4)) = o;
}

// ---------------------------------------------------------------------------
// K1: QKV + attention. Block = 256 thr = 4 waves = 4 heads of one window-half.
// ZERO __syncthreads: every wave is fully independent (x read from global with
// in-register bf16 convert; per-wave LDS scratch only; o written to global).
// blockIdx = (window - win0)*2 + half; wave h = half*4 + wave.
// Per-wave LDS (u16 units): vt[32][68]=2176 | pq[64][34]+pk[64][34]=4352,
//   overlaid by P[64][68]=4352 after ALL pq/pk fragment reads are hoisted
//   into registers (aq[4]/bk[4]) -- same-wave DS order + sH aliasing makes
//   the overlay safe (round-6 bug: aq reads interleaved with P writes).
// 4 x 6528 u16 = 52224 B/block -> 3 blocks/CU = 12 independent waves/CU.
// ---------------------------------------------------------------------------
__global__ __launch_bounds__(256, 3) void qkv_attn_kernel(
    const float* __restrict__ X,      // [131072][256] fp32
    const float* __restrict__ bmP,    // [64][8][64][64] fp32 (permuted)
    const float* __restrict__ lsc,    // [8] fp32
    const u16*  __restrict__ Wqb,     // [768][256] bf16
    const float* __restrict__ qb, const float* __restrict__ vbias,
    int win0,
    u16* __restrict__ O) {            // chunk-local [nwin*64][256] bf16
  __shared__ __attribute__((aligned(16))) u16 sH[4][6528];

  const int blk  = blockIdx.x;
  const int bw   = win0 + (blk >> 1);   // global window
  const int half = blk & 1;
  const int tid  = threadIdx.x;
  const int wave = tid >> 6, lane = tid & 63;
  const int l15 = lane & 15, l4 = lane >> 4;
  const int h = half * 4 + wave;        // head 0..7
  const int w = bw & 63;                // mask window index

  u16* vt = &sH[wave][0];       // [32][68] V^T (d, token)
  u16* pq = &sH[wave][2176];    // [64][34] normalized Q
  u16* pk = &sH[wave][4352];    // [64][34] normalized K
  u16* pP = &sH[wave][2176];    // [64][68] P, overlays pq+pk

  const float* xbase = X + (size_t)(bw * 64) * 256;

  // ---- Phase B: QKV GEMM for head h. A from global fp32 (convert in-reg).
  f32x4 acc[4][6];
#pragma unroll
  for (int mi = 0; mi < 4; ++mi)
#pragma unroll
    for (int nj = 0; nj < 6; ++nj) acc[mi][nj] = (f32x4){0.f, 0.f, 0.f, 0.f};

  const int rb[6] = {h * 32, h * 32 + 16, 256 + h * 32, 256 + h * 32 + 16,
                     512 + h * 32, 512 + h * 32 + 16};
#pragma unroll
  for (int kf = 0; kf < 8; ++kf) {
    short8 af[4];
#pragma unroll
    for (int mi = 0; mi < 4; ++mi) {
      const float* xr = xbase + (size_t)(mi * 16 + l15) * 256 + kf * 32 + l4 * 8;
      const float4 a0 = *(const float4*)(xr);
      const float4 a1 = *(const float4*)(xr + 4);
      af[mi] = cvt8(a0, a1);
    }
#pragma unroll
    for (int nj = 0; nj < 6; ++nj) {
      const short8 bf = *(const short8*)(
          Wqb + (size_t)(rb[nj] + l15) * 256 + kf * 32 + l4 * 8);
#pragma unroll
      for (int mi = 0; mi < 4; ++mi)
        acc[mi][nj] = __builtin_amdgcn_mfma_f32_16x16x32_bf16(af[mi], bf, acc[mi][nj], 0, 0, 0);
    }
  }

  // ---- epilogue: normalize q,k rows in-register -> pq/pk; V+bias -> vt
  {
    const float qb0 = qb[h * 32 + l15];
    const float qb1 = qb[h * 32 + 16 + l15];
#pragma unroll
    for (int mi = 0; mi < 4; ++mi)
#pragma unroll
      for (int r = 0; r < 4; ++r) {
        const float v0 = acc[mi][0][r] + qb0;
        const float v1 = acc[mi][1][r] + qb1;
        float ss = v0 * v0 + v1 * v1;
        ss += __shfl_xor(ss, 1); ss += __shfl_xor(ss, 2);
        ss += __shfl_xor(ss, 4); ss += __shfl_xor(ss, 8);
        const float inv = 1.f / fmaxf(sqrtf(ss), 1e-12f);
        const int m = mi * 16 + l4 * 4 + r;
        pq[m * 34 + l15]      = f2bf(v0 * inv);
        pq[m * 34 + 16 + l15] = f2bf(v1 * inv);
      }
#pragma unroll
    for (int mi = 0; mi < 4; ++mi)
#pragma unroll
      for (int r = 0; r < 4; ++r) {
        const float v0 = acc[mi][2][r];
        const float v1 = acc[mi][3][r];
        float ss = v0 * v0 + v1 * v1;
        ss += __shfl_xor(ss, 1); ss += __shfl_xor(ss, 2);
        ss += __shfl_xor(ss, 4); ss += __shfl_xor(ss, 8);
        const float inv = 1.f / fmaxf(sqrtf(ss), 1e-12f);
        const int m = mi * 16 + l4 * 4 + r;
        pk[m * 34 + l15]      = f2bf(v0 * inv);
        pk[m * 34 + 16 + l15] = f2bf(v1 * inv);
      }
    const float vb0 = vbias[h * 32 + l15];
    const float vb1 = vbias[h * 32 + 16 + l15];
#pragma unroll
    for (int mi = 0; mi < 4; ++mi)
#pragma unroll
      for (int r = 0; r < 4; ++r) {
        const int m = mi * 16 + l4 * 4 + r;
        vt[l15 * 68 + m]        = f2bf(acc[mi][4][r] + vb0);
        vt[(16 + l15) * 68 + m] = f2bf(acc[mi][5][r] + vb1);
      }
  }

  // ---- Phase C: S -> softmax -> P (1/sum deferred) -> PV, all wave-private
  const float scale = __expf(fminf(lsc[h], 4.60517018598809136804f));
  const float* bmbase = bmP + ((size_t)(w * 8 + h)) * 4096 + l15 * 4;
  float is_[4][4];

  // Hoist ALL pq/pk fragment reads above any pP write (overlay safety).
  short8 aq[4], bk[4];
#pragma unroll
  for (int j = 0; j < 4; ++j)
    bk[j] = *(const short8*)&pk[(j * 16 + l15) * 34 + l4 * 8];
#pragma unroll
  for (int i = 0; i < 4; ++i)
    aq[i] = *(const short8*)&pq[(i * 16 + l15) * 34 + l4 * 8];

#pragma unroll
  for (int i = 0; i < 4; ++i) {
    float4 bmv[4];
#pragma unroll
    for (int r = 0; r < 4; ++r)
      bmv[r] = *(const float4*)(bmbase + (size_t)(i * 16 + l4 * 4 + r) * 64);
    f32x4 s4[4];
    __builtin_amdgcn_s_setprio(1);
#pragma unroll
    for (int j = 0; j < 4; ++j) {
      const f32x4 z = {0.f, 0.f, 0.f, 0.f};
      s4[j] = __builtin_amdgcn_mfma_f32_16x16x32_bf16(aq[i], bk[j], z, 0, 0, 0);
    }
    __builtin_amdgcn_s_setprio(0);
#pragma unroll
    for (int r = 0; r < 4; ++r) {
      const int m = i * 16 + l4 * 4 + r;
      float v0[4]; float mx = -3.0e38f;
#pragma unroll
      for (int j = 0; j < 4; ++j) {
        const float sv = s4[j][r] * scale + bmv[r][j];
        v0[j] = sv; mx = fmaxf(mx, sv);
      }
      mx = fmaxf(mx, __shfl_xor(mx, 1)); mx = fmaxf(mx, __shfl_xor(mx, 2));
      mx = fmaxf(mx, __shfl_xor(mx, 4)); mx = fmaxf(mx, __shfl_xor(mx, 8));
      float sum = 0.f;
#pragma unroll
      for (int j = 0; j < 4; ++j) { v0[j] = __expf(v0[j] - mx); sum += v0[j]; }
      sum += __shfl_xor(sum, 1); sum += __shfl_xor(sum, 2);
      sum += __shfl_xor(sum, 4); sum += __shfl_xor(sum, 8);
      is_[i][r] = 1.f / sum;
#pragma unroll
      for (int j = 0; j < 4; ++j)
        pP[m * 68 + j * 16 + l15] = f2bf(v0[j]);   // unnormalized (<=1)
    }
  }

  // O = P @ V : 4 m-tiles x 2 d-tiles x 2 k-steps; scale rows by is_ at store
  f32x4 oa[4][2];
#pragma unroll
  for (int i = 0; i < 4; ++i)
#pragma unroll
    for (int nb = 0; nb < 2; ++nb) oa[i][nb] = (f32x4){0.f, 0.f, 0.f, 0.f};
#pragma unroll
  for (int kb = 0; kb < 2; ++kb) {
    short8 pa[4];
#pragma unroll
    for (int i = 0; i < 4; ++i)
      pa[i] = *(const short8*)&pP[(i * 16 + l15) * 68 + kb * 32 + l4 * 8];
    __builtin_amdgcn_s_setprio(1);
#pragma unroll
    for (int nb = 0; nb < 2; ++nb) {
      const short8 vb8 = *(const short8*)&vt[(nb * 16 + l15) * 68 + kb * 32 + l4 * 8];
#pragma unroll
      for (int i = 0; i < 4; ++i)
        oa[i][nb] = __builtin_amdgcn_mfma_f32_16x16x32_bf16(pa[i], vb8, oa[i][nb], 0, 0, 0);
    }
    __builtin_amdgcn_s_setprio(0);
  }

  u16* obase = O + ((size_t)(blk >> 1) * 64) * 256 + h * 32;
#pragma unroll
  for (int i = 0; i < 4; ++i)
#pragma unroll
    for (int nb = 0; nb < 2; ++nb)
#pragma unroll
      for (int r = 0; r < 4; ++r) {
        const int m = i * 16 + l4 * 4 + r;
        obase[(size_t)m * 256 + nb * 16 + l15] = f2bf(oa[i][nb][r] * is_[i][r]);
      }
}

// ---------------------------------------------------------------------------
// K2: proj GEMM. out[M][256] = O[M][256] @ Wp^T + pb. No LDS; A frags straight
// from global (L2), B from L2-resident Wpb. Block = 128 rows x 128 cols,
// 4 waves each 32 rows x 128 cols. Memory-bound streaming (201 MB).
// ---------------------------------------------------------------------------
__global__ __launch_bounds__(256) void proj_kernel(
    const u16* __restrict__ O, const u16* __restrict__ Wpb,
    const float* __restrict__ pb, float* __restrict__ out) {
  const int tid = threadIdx.x;
  const int wave = tid >> 6, lane = tid & 63;
  const int l15 = lane & 15, l4 = lane >> 4;
  const int mt = blockIdx.x >> 1, nt = blockIdx.x & 1;
  const int m0 = mt * 128 + wave * 32;
  const int n0 = nt * 128;

  const u16* ab = O + (size_t)(m0 + l15) * 256 + l4 * 8;
  f32x4 acc[2][8];
#pragma unroll
  for (int mi = 0; mi < 2; ++mi)
#pragma unroll
    for (int nj = 0; nj < 8; ++nj) acc[mi][nj] = (f32x4){0.f, 0.f, 0.f, 0.f};

#pragma unroll
  for (int kf = 0; kf < 8; ++kf) {
    short8 af[2];
    af[0] = *(const short8*)(ab + kf * 32);
    af[1] = *(const short8*)(ab + (size_t)16 * 256 + kf * 32);
#pragma unroll
    for (int nj = 0; nj < 8; ++nj) {
      const short8 bf = *(const short8*)(
          Wpb + (size_t)(n0 + nj * 16 + l15) * 256 + kf * 32 + l4 * 8);
      acc[0][nj] = __builtin_amdgcn_mfma_f32_16x16x32_bf16(af[0], bf, acc[0][nj], 0, 0, 0);
      acc[1][nj] = __builtin_amdgcn_mfma_f32_16x16x32_bf16(af[1], bf, acc[1][nj], 0, 0, 0);
    }
  }
#pragma unroll
  for (int mi = 0; mi < 2; ++mi)
#pragma unroll
    for (int nj = 0; nj < 8; ++nj) {
      const int n = n0 + nj * 16 + l15;
      const float bias = pb[n];
#pragma unroll
      for (int r = 0; r < 4; ++r) {
        const int m = m0 + mi * 16 + l4 * 4 + r;
        out[(size_t)m * 256 + n] = acc[mi][nj][r] + bias;
      }
    }
}

// ---------------------------------------------------------------------------
// ws layout: [0,16K) table | [256K,640K) Wqkv bf16 | [704K,832K) Wproj bf16 |
// [1M,9M) bmP fp32 | [16M, 16M+67M/nch) O bf16 chunk buffer.
// ---------------------------------------------------------------------------
extern "C" void kernel_launch(void* const* d_in, const int* in_sizes, int n_in,
                              void* d_out, int out_size, void* d_ws, size_t ws_size,
                              hipStream_t stream) {
  (void)in_sizes; (void)n_in; (void)out_size;
  const float* x    = (const float*)d_in[0];
  const float* mask = (const float*)d_in[1];
  const float* qkvw = (const float*)d_in[2];
  const float* qb   = (const float*)d_in[3];
  const float* vb   = (const float*)d_in[4];
  const float* lsc  = (const float*)d_in[5];
  const float* w1   = (const float*)d_in[6];
  const float* b1   = (const float*)d_in[7];
  const float* w2   = (const float*)d_in[8];
  const float* pw   = (const float*)d_in[9];
  const float* pb   = (const float*)d_in[10];
  const float* ct   = (const float*)d_in[11];
  const int* rel    = (const int*)d_in[12];
  float* out = (float*)d_out;

  char* ws = (char*)d_ws;
  float* table = (float*)(ws);
  u16* Wqb = (u16*)(ws + 262144);          // 393,216 B
  u16* Wpb = (u16*)(ws + 720896);          // 131,072 B
  float* bmP = (float*)(ws + (1 << 20));   // 8 MB
  u16* O = (u16*)(ws + (16u << 20));       // up to 67 MB

  // chunking: smallest nch in {1,2,4,8} whose O-chunk fits the workspace
  int nch = 8;
  for (int c = 1; c <= 8; c <<= 1) {
    if (ws_size >= (size_t)(16u << 20) + 67108864ull / c) { nch = c; break; }
  }
  const int CHUNK_WIN = 2048 / nch;

  wcvt_kernel<<<256, 256, 0, stream>>>(qkvw, pw, Wqb, Wpb);
  cpb_kernel<<<225, 256, 0, stream>>>(ct, w1, b1, w2, table);
  bm_kernel<<<2048, 256, 0, stream>>>(table, rel, mask, bmP);

  for (int c = 0; c < nch; ++c) {
    qkv_attn_kernel<<<CHUNK_WIN * 2, 256, 0, stream>>>(
        x, bmP, lsc, Wqb, qb, vb, c * CHUNK_WIN, O);
    proj_kernel<<<CHUNK_WIN, 256, 0, stream>>>(
        O, Wpb, pb, out + (size_t)c * CHUNK_WIN * 64 * 256);
  }
}

// Round 8
// 433.382 us; speedup vs baseline: 1.4873x; 1.4873x over previous
//
#include <hip/hip_runtime.h>
#include <hip/hip_bf16.h>

typedef unsigned short u16;
typedef unsigned int   u32;
typedef __attribute__((ext_vector_type(8))) short short8;   // 8 x bf16 bits (4 VGPR)
typedef __attribute__((ext_vector_type(4))) float f32x4;    // MFMA 16x16 accumulator

// round-to-nearest-even f32 -> bf16 (finite inputs only)
__device__ __forceinline__ u16 f2bf(float f) {
  u32 u = __float_as_uint(f);
  u32 r = (u + 0x7fffu + ((u >> 16) & 1u)) >> 16;
  return (u16)r;
}
// packed RNE f32x2 -> bf16x2 in one instruction (T12 recipe)
__device__ __forceinline__ u32 cvtpk(float lo, float hi) {
  u32 r;
  asm("v_cvt_pk_bf16_f32 %0, %1, %2" : "=v"(r) : "v"(lo), "v"(hi));
  return r;
}

#define LOG2E 1.4426950408889634f

// ---------------------------------------------------------------------------
// Weight pre-convert: qkv_w flat; proj_w with k-dim permuted within 32-blocks
// (pos p holds channel c(p) = ((p&1)<<4)|((p>>1)&15)) to match o's packed
// channel-interleaved layout.
// ---------------------------------------------------------------------------
__global__ __launch_bounds__(256) void wcvt_kernel(
    const float* __restrict__ qkvw, const float* __restrict__ pw,
    u16* __restrict__ wq, u16* __restrict__ wp) {
  const int e = (blockIdx.x * 256 + threadIdx.x) * 4;  // 256 blocks -> 262144
  if (e < 196608) {
    const float4 v = *(const float4*)(qkvw + e);
    u32 w0 = cvtpk(v.x, v.y), w1 = cvtpk(v.z, v.w);
    *(uint2*)(wq + e) = make_uint2(w0, w1);
  } else {
    const int e2 = e - 196608;
#pragma unroll
    for (int q = 0; q < 4; ++q) {
      const int idx = e2 + q;
      const int n = idx >> 8, p = idx & 255;
      const int c = (p & 0xE0) | ((p & 1) << 4) | ((p >> 1) & 15);
      wp[idx] = f2bf(pw[n * 256 + c]);
    }
  }
}

// ---------------------------------------------------------------------------
// CPB MLP: table[225][8] = relu(coords @ w1^T + b1) @ w2^T   (fp32 math)
// ---------------------------------------------------------------------------
__global__ __launch_bounds__(256) void cpb_kernel(
    const float* __restrict__ ct, const float* __restrict__ w1,
    const float* __restrict__ b1, const float* __restrict__ w2,
    float* __restrict__ table) {
  const int r = blockIdx.x;            // 0..224
  const int t = threadIdx.x;           // 0..255
  const int lane = t & 63, wave = t >> 6;
  const float c0 = ct[r * 2 + 0];
  const float c1 = ct[r * 2 + 1];
  float acc[8] = {0.f, 0.f, 0.f, 0.f, 0.f, 0.f, 0.f, 0.f};
  for (int j = t; j < 512; j += 256) {
    float hid = fmaxf(c0 * w1[j * 2] + c1 * w1[j * 2 + 1] + b1[j], 0.f);
#pragma unroll
    for (int hh = 0; hh < 8; ++hh) acc[hh] += hid * w2[hh * 512 + j];
  }
#pragma unroll
  for (int hh = 0; hh < 8; ++hh)
#pragma unroll
    for (int off = 1; off < 64; off <<= 1) acc[hh] += __shfl_xor(acc[hh], off);
  __shared__ float red[4][8];
  if (lane == 0)
#pragma unroll
    for (int hh = 0; hh < 8; ++hh) red[wave][hh] = acc[hh];
  __syncthreads();
  if (t < 8) table[r * 8 + t] = red[0][t] + red[1][t] + red[2][t] + red[3][t];
}

// ---------------------------------------------------------------------------
// bmP[w][h][m][l][j] = (16*sigmoid(table[rel[m*64+j*16+l]][h]) + mask) * LOG2E
// (log2-domain so softmax uses exp2 directly). Permuted for float4-per-lane.
// ---------------------------------------------------------------------------
__global__ __launch_bounds__(256) void bm_kernel(
    const float* __restrict__ table, const int* __restrict__ rel,
    const float* __restrict__ mask, float* __restrict__ bmP) {
  const int g = blockIdx.x * 256 + threadIdx.x;   // 0..524287
  const int w = g >> 13;
  const int h = (g >> 10) & 7;
  const int m = (g >> 4) & 63;
  const int l = g & 15;
  float4 o;
#pragma unroll
  for (int j = 0; j < 4; ++j) {
    const int c = j * 16 + l;
    const float t = table[rel[m * 64 + c] * 8 + h];
    o[j] = (16.f / (1.f + __expf(-t)) + mask[(size_t)w * 4096 + m * 64 + c]) * LOG2E;
  }
  *(float4*)(bmP + ((((size_t)w * 8 + h) * 64 + m) * 64 + l * 4)) = o;
}

// ---------------------------------------------------------------------------
// Fused per-window kernel, WAVE = HEAD (512 thr, 8 waves) -- round-4 champion
// structure with: packed cvt_pk bf16 stores (layout-permuted operand pairs),
// conflict-free 16B-aligned LDS strides, exp2-domain softmax, deferred 1/sum,
// rsqrt norm, 2-deep weight prefetch. 3 barriers.
// Channel perm (q/k, S k-dim):  pos 2c = tile0 ch c, 2c+1 = tile1 ch c.
// Token perm (P & V^T, PV k-dim): t' = (t%16)*4 + t/16.
// o channel perm (proj k-dim, matches permuted Wpb): p = 2*(c%16) + c/16.
// LDS: sA 40960 B (x[8][64][40] -> o[64][264]) + 8 x 14848 B = 159744 B.
// ---------------------------------------------------------------------------
__global__ __launch_bounds__(512, 2) void fused_kernel(
    const float* __restrict__ X,      // [131072][256] fp32
    const float* __restrict__ bmP,    // [64][8][64][64] fp32 (log2-domain)
    const float* __restrict__ lsc,    // [8] fp32
    const u16*  __restrict__ Wqb,     // [768][256] bf16
    const float* __restrict__ qb, const float* __restrict__ vbias,
    const u16*  __restrict__ Wpb,     // [256][256] bf16 (k-permuted)
    const float* __restrict__ pb,     // [256] fp32
    float* __restrict__ out) {        // [131072][256] fp32
  __shared__ __attribute__((aligned(16))) u16 sA[20480];     // x[8][64][40] -> o[64][264]
  __shared__ __attribute__((aligned(16))) u16 sW[8][7424];   // vt[32][72] | pq[64][40]+pk[64][40] -> P[64][72]

  const int bw = blockIdx.x;        // window 0..2047
  const int w  = bw & 63;           // mask window index
  const int tid  = threadIdx.x;
  const int wave = tid >> 6, lane = tid & 63;
  const int l15 = lane & 15, l4 = lane >> 4;
  const int h = wave;               // wave == head

  // ---- Phase A: stage x -> bf16 sA[kf][row][40] (packed cvt, b64 stores)
  {
    const int cq  = tid & 7;        // 8 chunks of 4 fp32 = 32 cols
    const int rlo = tid >> 3;       // 0..63
    const float* xrow = X + ((size_t)bw * 64 + rlo) * 256;
#pragma unroll
    for (int kf = 0; kf < 8; ++kf) {
      const float4 xv = *(const float4*)(xrow + kf * 32 + cq * 4);
      *(uint2*)&sA[kf * 2560 + rlo * 40 + cq * 4] =
          make_uint2(cvtpk(xv.x, xv.y), cvtpk(xv.z, xv.w));
    }
  }
  __syncthreads();

  u16* vt = &sW[wave][0];      // [32][72] V^T (d, token-perm)
  u16* pq = &sW[wave][2304];   // [64][40] normalized Q (channel-perm)
  u16* pk = &sW[wave][4864];   // [64][40] normalized K (channel-perm)
  u16* pP = &sW[wave][2304];   // [64][72] P (token-perm), overlays pq+pk

  f32x4 oa[4][2];              // PV result -> sA after barrier #2
  float is_[4][4];             // deferred 1/sum

  // ================= wave-private B+C stretch =================
  {
    // ---- Phase B: QKV GEMM for head h: 6 n-tiles x 4 m-tiles x K=256
    const int rb[6] = {h * 32, h * 32 + 16, 256 + h * 32, 256 + h * 32 + 16,
                       512 + h * 32, 512 + h * 32 + 16};
    const u16* wb[6];
#pragma unroll
    for (int nj = 0; nj < 6; ++nj)
      wb[nj] = Wqb + (size_t)(rb[nj] + l15) * 256 + l4 * 8;

    f32x4 acc[4][6];
#pragma unroll
    for (int mi = 0; mi < 4; ++mi)
#pragma unroll
      for (int nj = 0; nj < 6; ++nj) acc[mi][nj] = (f32x4){0.f, 0.f, 0.f, 0.f};

    short8 bfA[6], bfB[6];      // 2-deep weight prefetch
#pragma unroll
    for (int nj = 0; nj < 6; ++nj) bfA[nj] = *(const short8*)(wb[nj]);
#pragma unroll
    for (int nj = 0; nj < 6; ++nj) bfB[nj] = *(const short8*)(wb[nj] + 32);

#pragma unroll
    for (int kf = 0; kf < 8; ++kf) {
      short8 af[4];
#pragma unroll
      for (int mi = 0; mi < 4; ++mi)
        af[mi] = *(const short8*)&sA[kf * 2560 + (mi * 16 + l15) * 40 + l4 * 8];
      __builtin_amdgcn_s_setprio(1);
      if ((kf & 1) == 0) {
#pragma unroll
        for (int nj = 0; nj < 6; ++nj)
#pragma unroll
          for (int mi = 0; mi < 4; ++mi)
            acc[mi][nj] = __builtin_amdgcn_mfma_f32_16x16x32_bf16(af[mi], bfA[nj], acc[mi][nj], 0, 0, 0);
        __builtin_amdgcn_s_setprio(0);
        if (kf < 6) {
#pragma unroll
          for (int nj = 0; nj < 6; ++nj)
            bfA[nj] = *(const short8*)(wb[nj] + (kf + 2) * 32);
        }
      } else {
#pragma unroll
        for (int nj = 0; nj < 6; ++nj)
#pragma unroll
          for (int mi = 0; mi < 4; ++mi)
            acc[mi][nj] = __builtin_amdgcn_mfma_f32_16x16x32_bf16(af[mi], bfB[nj], acc[mi][nj], 0, 0, 0);
        __builtin_amdgcn_s_setprio(0);
        if (kf < 6) {
#pragma unroll
          for (int nj = 0; nj < 6; ++nj)
            bfB[nj] = *(const short8*)(wb[nj] + (kf + 2) * 32);
        }
      }
    }

    // ---- epilogue: q/k row-norm -> packed channel-interleaved stage; V -> vt
    {
      const float qb0 = qb[h * 32 + l15];
      const float qb1 = qb[h * 32 + 16 + l15];
#pragma unroll
      for (int mi = 0; mi < 4; ++mi)
#pragma unroll
        for (int r = 0; r < 4; ++r) {
          const float v0 = acc[mi][0][r] + qb0;
          const float v1 = acc[mi][1][r] + qb1;
          float ss = v0 * v0 + v1 * v1;
          ss += __shfl_xor(ss, 1); ss += __shfl_xor(ss, 2);
          ss += __shfl_xor(ss, 4); ss += __shfl_xor(ss, 8);
          const float inv = __frsqrt_rn(fmaxf(ss, 1e-24f));
          const int m = mi * 16 + l4 * 4 + r;
          *(u32*)&pq[m * 40 + l15 * 2] = cvtpk(v0 * inv, v1 * inv);
        }
#pragma unroll
      for (int mi = 0; mi < 4; ++mi)
#pragma unroll
        for (int r = 0; r < 4; ++r) {
          const float v0 = acc[mi][2][r];
          const float v1 = acc[mi][3][r];
          float ss = v0 * v0 + v1 * v1;
          ss += __shfl_xor(ss, 1); ss += __shfl_xor(ss, 2);
          ss += __shfl_xor(ss, 4); ss += __shfl_xor(ss, 8);
          const float inv = __frsqrt_rn(fmaxf(ss, 1e-24f));
          const int m = mi * 16 + l4 * 4 + r;
          *(u32*)&pk[m * 40 + l15 * 2] = cvtpk(v0 * inv, v1 * inv);
        }
      // V: bias add, token-permuted transpose, packed b64 stores
      const float vb0 = vbias[h * 32 + l15];
      const float vb1 = vbias[h * 32 + 16 + l15];
#pragma unroll
      for (int nb = 0; nb < 2; ++nb) {
        const float vb = nb ? vb1 : vb0;
        u16* vrow = vt + (nb * 16 + l15) * 72 + l4 * 16;
#pragma unroll
        for (int r = 0; r < 4; ++r) {
          const u32 w0 = cvtpk(acc[0][4 + nb][r] + vb, acc[1][4 + nb][r] + vb);
          const u32 w1 = cvtpk(acc[2][4 + nb][r] + vb, acc[3][4 + nb][r] + vb);
          *(uint2*)&vrow[r * 4] = make_uint2(w0, w1);
        }
      }
    }

    // ---- Phase C: S -> softmax(exp2) -> P -> PV, all wave-private
    // bias+mask loads issued first (independent) to hide L2/L3
    const float* bmbase = bmP + ((size_t)(w * 8 + h)) * 4096 + l15 * 4;
    float4 bmv[4][4];
#pragma unroll
    for (int i = 0; i < 4; ++i)
#pragma unroll
      for (int r = 0; r < 4; ++r)
        bmv[i][r] = *(const float4*)(bmbase + (size_t)(i * 16 + l4 * 4 + r) * 64);

    // hoist ALL pq/pk fragment reads above any pP write (overlay safety)
    short8 aq[4], bk[4];
#pragma unroll
    for (int j = 0; j < 4; ++j)
      bk[j] = *(const short8*)&pk[(j * 16 + l15) * 40 + l4 * 8];
#pragma unroll
    for (int i = 0; i < 4; ++i)
      aq[i] = *(const short8*)&pq[(i * 16 + l15) * 40 + l4 * 8];

    f32x4 s[4][4];
    __builtin_amdgcn_s_setprio(1);
#pragma unroll
    for (int i = 0; i < 4; ++i)
#pragma unroll
      for (int j = 0; j < 4; ++j) {
        const f32x4 z = {0.f, 0.f, 0.f, 0.f};
        s[i][j] = __builtin_amdgcn_mfma_f32_16x16x32_bf16(aq[i], bk[j], z, 0, 0, 0);
      }
    __builtin_amdgcn_s_setprio(0);

    const float sc2 = __expf(fminf(lsc[h], 4.60517018598809136804f)) * LOG2E;

#pragma unroll
    for (int i = 0; i < 4; ++i)
#pragma unroll
      for (int r = 0; r < 4; ++r) {
        const int m = i * 16 + l4 * 4 + r;
        float v0[4]; float mx = -3.0e38f;
#pragma unroll
        for (int j = 0; j < 4; ++j) {
          const float sv = s[i][j][r] * sc2 + bmv[i][r][j];   // log2 domain
          v0[j] = sv; mx = fmaxf(mx, sv);
        }
        mx = fmaxf(mx, __shfl_xor(mx, 1)); mx = fmaxf(mx, __shfl_xor(mx, 2));
        mx = fmaxf(mx, __shfl_xor(mx, 4)); mx = fmaxf(mx, __shfl_xor(mx, 8));
        float sum = 0.f;
#pragma unroll
        for (int j = 0; j < 4; ++j) { v0[j] = exp2f(v0[j] - mx); sum += v0[j]; }
        sum += __shfl_xor(sum, 1); sum += __shfl_xor(sum, 2);
        sum += __shfl_xor(sum, 4); sum += __shfl_xor(sum, 8);
        is_[i][r] = 1.f / sum;
        // token-permuted P row: lane's 4 tokens are contiguous -> one b64
        *(uint2*)&pP[m * 72 + l15 * 4] =
            make_uint2(cvtpk(v0[0], v0[1]), cvtpk(v0[2], v0[3]));
      }

    // O = P @ V : 4 m-tiles x 2 d-tiles x 2 k-steps (token-perm consistent)
#pragma unroll
    for (int i = 0; i < 4; ++i)
#pragma unroll
      for (int nb = 0; nb < 2; ++nb) oa[i][nb] = (f32x4){0.f, 0.f, 0.f, 0.f};
#pragma unroll
    for (int kb = 0; kb < 2; ++kb) {
      short8 pa[4];
#pragma unroll
      for (int i = 0; i < 4; ++i)
        pa[i] = *(const short8*)&pP[(i * 16 + l15) * 72 + kb * 32 + l4 * 8];
      __builtin_amdgcn_s_setprio(1);
#pragma unroll
      for (int nb = 0; nb < 2; ++nb) {
        const short8 vb8 = *(const short8*)&vt[(nb * 16 + l15) * 72 + kb * 32 + l4 * 8];
#pragma unroll
        for (int i = 0; i < 4; ++i)
          oa[i][nb] = __builtin_amdgcn_mfma_f32_16x16x32_bf16(pa[i], vb8, oa[i][nb], 0, 0, 0);
      }
      __builtin_amdgcn_s_setprio(0);
    }
  }
  // ================= end wave-private stretch =================

  __syncthreads();   // all waves done reading sA (x) -> safe to overwrite with o

  // o -> sA, channel-interleaved pairs (nb0,nb1) packed per dword
#pragma unroll
  for (int i = 0; i < 4; ++i)
#pragma unroll
    for (int r = 0; r < 4; ++r) {
      const int m = i * 16 + l4 * 4 + r;
      const float is = is_[i][r];
      *(u32*)&sA[m * 264 + h * 32 + l15 * 2] =
          cvtpk(oa[i][0][r] * is, oa[i][1][r] * is);
    }
  __syncthreads();   // o complete across all waves

  // ---- Phase D: proj. wave owns output cols [wave*32,+32), K=256 (permuted)
  {
    const int n0 = wave * 32;
    const u16* pbase = Wpb + (size_t)(n0 + l15) * 256 + l4 * 8;
    f32x4 pacc[4][2];
#pragma unroll
    for (int mi = 0; mi < 4; ++mi)
#pragma unroll
      for (int nj = 0; nj < 2; ++nj) pacc[mi][nj] = (f32x4){0.f, 0.f, 0.f, 0.f};

    short8 bfr_cur[2];
#pragma unroll
    for (int nj = 0; nj < 2; ++nj)
      bfr_cur[nj] = *(const short8*)(pbase + (size_t)(nj * 16) * 256);

#pragma unroll
    for (int ks = 0; ks < 8; ++ks) {
      const int k0 = ks * 32;
      short8 afr[4];
#pragma unroll
      for (int mi = 0; mi < 4; ++mi)
        afr[mi] = *(const short8*)&sA[(mi * 16 + l15) * 264 + k0 + l4 * 8];
      short8 bfr_nxt[2];
      if (ks < 7) {
#pragma unroll
        for (int nj = 0; nj < 2; ++nj)
          bfr_nxt[nj] = *(const short8*)(pbase + (size_t)(nj * 16) * 256 + k0 + 32);
      }
#pragma unroll
      for (int nj = 0; nj < 2; ++nj)
#pragma unroll
        for (int mi = 0; mi < 4; ++mi)
          pacc[mi][nj] = __builtin_amdgcn_mfma_f32_16x16x32_bf16(afr[mi], bfr_cur[nj], pacc[mi][nj], 0, 0, 0);
      if (ks < 7) {
#pragma unroll
        for (int nj = 0; nj < 2; ++nj) bfr_cur[nj] = bfr_nxt[nj];
      }
    }
    float* orow = out + (size_t)bw * 64 * 256;
#pragma unroll
    for (int mi = 0; mi < 4; ++mi)
#pragma unroll
      for (int nj = 0; nj < 2; ++nj) {
        const int n = n0 + nj * 16 + l15;
        const float bias = pb[n];
#pragma unroll
        for (int r = 0; r < 4; ++r) {
          const int m = mi * 16 + l4 * 4 + r;
          orow[(size_t)m * 256 + n] = pacc[mi][nj][r] + bias;
        }
      }
  }
}

// ---------------------------------------------------------------------------
// ws layout: [0,16K) table | [256K,640K) Wqkv bf16 | [704K,832K) Wproj bf16 |
// [1M, 9M) bmP fp32.
// ---------------------------------------------------------------------------
extern "C" void kernel_launch(void* const* d_in, const int* in_sizes, int n_in,
                              void* d_out, int out_size, void* d_ws, size_t ws_size,
                              hipStream_t stream) {
  (void)in_sizes; (void)n_in; (void)out_size; (void)ws_size;
  const float* x    = (const float*)d_in[0];
  const float* mask = (const float*)d_in[1];
  const float* qkvw = (const float*)d_in[2];
  const float* qb   = (const float*)d_in[3];
  const float* vb   = (const float*)d_in[4];
  const float* lsc  = (const float*)d_in[5];
  const float* w1   = (const float*)d_in[6];
  const float* b1   = (const float*)d_in[7];
  const float* w2   = (const float*)d_in[8];
  const float* pw   = (const float*)d_in[9];
  const float* pb   = (const float*)d_in[10];
  const float* ct   = (const float*)d_in[11];
  const int* rel    = (const int*)d_in[12];
  float* out = (float*)d_out;

  char* ws = (char*)d_ws;
  float* table = (float*)(ws);
  u16* Wqb = (u16*)(ws + 262144);          // 393,216 B
  u16* Wpb = (u16*)(ws + 720896);          // 131,072 B
  float* bmP = (float*)(ws + (1 << 20));   // 8 MB

  wcvt_kernel<<<256, 256, 0, stream>>>(qkvw, pw, Wqb, Wpb);
  cpb_kernel<<<225, 256, 0, stream>>>(ct, w1, b1, w2, table);
  bm_kernel<<<2048, 256, 0, stream>>>(table, rel, mask, bmP);
  fused_kernel<<<2048, 512, 0, stream>>>(x, bmP, lsc, Wqb, qb, vb,
                                         Wpb, pb, out);
}